// Round 11
// baseline (173.836 us; speedup 1.0000x reference)
//
#include <hip/hip_runtime.h>

// Fused causal self-attention block, MI355X gfx950.
// B=2, T=2048, E=1024, H=16, D=64.
// 32x32x16 layouts (m74/m101): A[m=lane&31][k=(lane>>5)*8+j],
//   B[k=(lane>>5)*8+j][n=lane&31], C/D[col=lane&31, row=(reg&3)+8*(reg>>2)+4*(lane>>5)].
// R12 FAILED: per-lane global K/V frag loads = L1 transaction-bound; keep
//   global_load_lds staging.
// R13/14 (landed, attn ~41us): 16x16 + swizzled P LDS + native-cast f2b.
// R15 FAILED (65us): 1 wave/SIMD latency-bound. Need >=2 waves/SIMD.
// R16 (50.5us): 32x32 swapped-QK^T, in-register P repack (verified).
// R17 (44.5us): permlane32_swap repack + KVBLK=128.
// R18 (~41us): equalized ktmax across waves (+3us only).
// R20 (attn ~36us, total 172.7): split-K doubled waves/SIMD to 4 -> only
//   -1.4us. FALSIFIES issue-coverage theory. Re-derived cost model: per
//   CU-stage, 16 q-tile-subtile computations x 16 ds_read_b128 x 12cy =
//   3072 LDS-pipe cy -> ~22us of the ~36us wall. LDS READ PIPE is the
//   bottleneck; K/V frags are q-tile-independent.
// R21 (this round): 2 q-tiles (64 rows) PER WAVE -- K/V frags read once,
//   used for both tiles (LDS reads/CU-stage halved 3072->1536, below the
//   ~1700cy VALU floor). 512 blocks x 4 waves (256thr): wave=(slot a,
//   parity p); slot a owns q-tiles 4t+a and 4t+2+a -> ktmaxA=2t,
//   ktmaxB=2t+1 IDENTICAL for all waves. nk2=t+1 unchanged. V-frags
//   hoisted to regs once/stage. 64KB LDS, 2 blocks/CU, 2 waves/SIMD.
//   Split-K combine widened to 2 tiles (same verified pattern).

typedef unsigned short u16;
typedef unsigned int u32;
typedef __bf16 bf8 __attribute__((ext_vector_type(8)));
typedef float f32x4 __attribute__((ext_vector_type(4)));
typedef float f32x16 __attribute__((ext_vector_type(16)));
typedef u32 u32x4v __attribute__((ext_vector_type(4)));

__device__ __forceinline__ u16 f2b(float f) {
    return __builtin_bit_cast(u16, (__bf16)f);         // RNE
}

__device__ __forceinline__ u32 pk2(float lo, float hi) {
    return (u32)f2b(lo) | ((u32)f2b(hi) << 16);
}

__device__ __forceinline__ f32x4 mfma16(bf8 a, bf8 b, f32x4 c) {
    return __builtin_amdgcn_mfma_f32_16x16x32_bf16(a, b, c, 0, 0, 0);
}

__device__ __forceinline__ f32x16 mfma32(bf8 a, bf8 b, f32x16 c) {
    return __builtin_amdgcn_mfma_f32_32x32x16_bf16(a, b, c, 0, 0, 0);
}

__device__ __forceinline__ float fexp2(float x) {
    return __builtin_amdgcn_exp2f(x);                  // v_exp_f32
}

// a' = [a.lo31, b.lo31]; b' = [a.hi31, b.hi31]  (VALU cross-half exchange)
__device__ __forceinline__ void pl32swap(u32& a, u32& b) {
    asm("v_permlane32_swap_b32 %0, %1" : "+v"(a), "+v"(b));
}

// async global->LDS, 16B per lane. LDS dest must be wave-uniform base + lane*16.
__device__ __forceinline__ void gload_lds16(const u16* g, u16* l) {
    __builtin_amdgcn_global_load_lds(
        (__attribute__((address_space(1))) void*)(g),
        (__attribute__((address_space(3))) void*)(l), 16, 0, 0);
}

// ---------------- prep: x->bf16 convert + both weight transposes ----------------
__global__ __launch_bounds__(256) void k_prep(const float* __restrict__ x,
                                              const float* __restrict__ Wa,
                                              const float* __restrict__ Wp,
                                              u16* __restrict__ Xb,
                                              u16* __restrict__ WtA,
                                              u16* __restrict__ WtP) {
    __shared__ float tile[64][65];
    int id = blockIdx.x, t = threadIdx.x;
    if (id < 4096) {                         // convert 4 floats/thread
        int i = id * 256 + t;
        float4 v = ((const float4*)x)[i];
        ushort4 o;
        o.x = f2b(v.x); o.y = f2b(v.y); o.z = f2b(v.z); o.w = f2b(v.w);
        ((ushort4*)Xb)[i] = o;
        return;
    }
    const float* in; u16* out; int N, j;
    if (id < 4864) { j = id - 4096; in = Wa; out = WtA; N = 3072; }
    else           { j = id - 4864; in = Wp; out = WtP; N = 1024; }
    int k0 = (j & 15) * 64, n0 = (j >> 4) * 64;
    int c = t & 63, r0 = t >> 6;
#pragma unroll
    for (int i = 0; i < 16; ++i) {
        int r = r0 + i * 4;
        tile[r][c] = in[(size_t)(k0 + r) * N + n0 + c];
    }
    __syncthreads();
#pragma unroll
    for (int i = 0; i < 16; ++i) {
        int r = r0 + i * 4;
        out[(size_t)(n0 + r) * 1024 + k0 + c] = f2b(tile[c][r]);
    }
}

// =====================================================================
// GEMM core v2 (unchanged from R13/14): C[128x128]/block, dbuf LDS,
// 1 barrier/K-step, XOR-swizzled images.
// =====================================================================
#define GEMM_STAGE(GA0, GA1, GB0, GB1, K, B)                                   \
    do {                                                                       \
        gload_lds16(GA0 + (K), As[B] + tid * 8);                               \
        gload_lds16(GA1 + (K), As[B] + (256 + tid) * 8);                       \
        gload_lds16(GB0 + (K), Bs[B] + tid * 8);                               \
        gload_lds16(GB1 + (K), Bs[B] + (256 + tid) * 8);                       \
    } while (0)

#define GEMM_CORE(Aptr, Bptr)                                                  \
    int tid = threadIdx.x;                                                     \
    int w = tid >> 6, lane = tid & 63, l16 = lane & 15, quad = lane >> 4;      \
    int m0 = blockIdx.x * 128, n0 = blockIdx.y * 128;                          \
    int wr = (w >> 1) * 64, wc = (w & 1) * 64;                                 \
    __shared__ u16 As[2][128 * 32];                                            \
    __shared__ u16 Bs[2][128 * 32];                                            \
    f32x4 acc[4][4];                                                           \
    _Pragma("unroll") for (int mi = 0; mi < 4; ++mi)                           \
        _Pragma("unroll") for (int ni = 0; ni < 4; ++ni)                       \
            _Pragma("unroll") for (int r = 0; r < 4; ++r) acc[mi][ni][r] = 0.f;\
    int srow0 = tid >> 2, srow1 = 64 + srow0;                                  \
    int slc = ((tid & 3) ^ ((tid >> 3) & 3)) * 8;   /* swizzled src chunk */   \
    const u16* gA0 = Aptr + (size_t)(m0 + srow0) * 1024 + slc;                 \
    const u16* gA1 = Aptr + (size_t)(m0 + srow1) * 1024 + slc;                 \
    const u16* gB0 = Bptr + (size_t)(n0 + srow0) * 1024 + slc;                 \
    const u16* gB1 = Bptr + (size_t)(n0 + srow1) * 1024 + slc;                 \
    int cq = (quad ^ ((l16 >> 1) & 3)) * 8;         /* frag phys chunk */      \
    GEMM_STAGE(gA0, gA1, gB0, gB1, 0, 0);                                      \
    for (int it = 0; it < 32; ++it) {                                          \
        int pb = it & 1;                                                       \
        __syncthreads();                  /* drains buf[pb] staging */         \
        bf8 af[4], bf[4];                                                      \
        _Pragma("unroll") for (int mi = 0; mi < 4; ++mi)                       \
            af[mi] = *(const bf8*)(As[pb] + (wr + mi * 16 + l16) * 32 + cq);   \
        _Pragma("unroll") for (int ni = 0; ni < 4; ++ni)                       \
            bf[ni] = *(const bf8*)(Bs[pb] + (wc + ni * 16 + l16) * 32 + cq);   \
        if (it < 31) GEMM_STAGE(gA0, gA1, gB0, gB1, (it + 1) * 32, pb ^ 1);    \
        _Pragma("unroll") for (int mi = 0; mi < 4; ++mi)                       \
            _Pragma("unroll") for (int ni = 0; ni < 4; ++ni)                   \
                acc[mi][ni] = mfma16(af[mi], bf[ni], acc[mi][ni]);             \
    }

// ---------------- QKV GEMM: [4096,1024] @ Wt[3072,1024] + bias ----------------
__global__ __launch_bounds__(256, 3) void k_qkv(const u16* __restrict__ Xb,
                                                const u16* __restrict__ WtA,
                                                const float* __restrict__ ba,
                                                u16* __restrict__ Qb,
                                                u16* __restrict__ Kb,
                                                u16* __restrict__ Vtb) {
    GEMM_CORE(Xb, WtA)
    int sel = n0 >> 10;                       // 0:Q 1:K 2:V (uniform per block)
    u16* dst = sel == 0 ? Qb : (sel == 1 ? Kb : Vtb);
    const float qs = 0.18033688011112042f;    // 0.125 * log2(e)
#pragma unroll
    for (int ni = 0; ni < 4; ++ni) {
        int n = n0 + wc + ni * 16 + l16;
        float bias = ba[n];
        int h = (n & 1023) >> 6;
        int d = n & 63;
#pragma unroll
        for (int mi = 0; mi < 4; ++mi)
#pragma unroll
            for (int r = 0; r < 4; ++r) {
                int m = m0 + wr + mi * 16 + quad * 4 + r;
                int bb = m >> 11, tt = m & 2047;
                float v = acc[mi][ni][r] + bias;
                size_t hb = (size_t)(bb * 16 + h);
                if (sel == 2)                             // V^T tiled
                    dst[hb * 131072 + (size_t)(tt >> 6) * 4096 + d * 64 + (tt & 63)] = f2b(v);
                else
                    dst[(hb * 2048 + tt) * 64 + d] =
                        f2b(sel == 0 ? v * qs : v);
            }
    }
}

// ---------------- proj GEMM: AO[4096,1024] @ WtP[1024,1024] + bias -> fp32 ----------------
__global__ __launch_bounds__(256, 3) void k_proj(const u16* __restrict__ AO,
                                                 const u16* __restrict__ WtP,
                                                 const float* __restrict__ bp,
                                                 float* __restrict__ out) {
    GEMM_CORE(AO, WtP)
#pragma unroll
    for (int ni = 0; ni < 4; ++ni) {
        int n = n0 + wc + ni * 16 + l16;
        float bias = bp[n];
#pragma unroll
        for (int mi = 0; mi < 4; ++mi)
#pragma unroll
            for (int r = 0; r < 4; ++r) {
                int m = m0 + wr + mi * 16 + quad * 4 + r;
                out[(size_t)m * 1024 + n] = acc[mi][ni][r] + bias;
            }
    }
}

// ---------------- flash attention (causal): 2 q-tiles/wave, split-K ----------------
// Block = 4 waves (256 thr), one head, q-rows [128t, 128t+128).
// Wave w = (slot a = w&1, parity p = w>>1). Slot a owns q-tiles
// tqA = 4t+a (ktmaxA = 2t) and tqB = 4t+2+a (ktmaxB = 2t+1) -- identical
// bounds for every wave. Parity p computes key-tiles kt === p (mod 2).
// Per stage: K-frags (8 b128) and V-frags (8 b128) read ONCE, feed BOTH
// q-tiles' MFMAs from registers (the R21 lever: LDS reads/CU-stage halved).
// Per active tile: S^T = mfma32(K, Q^T); exp2 (lane-local l, treed sum);
// P^T repack via v_permlane32_swap_b32; O^T += mfma32(V^T, P^T).
// End: parity-1 waves write (O^T,l)x2 to LDS; parity-0 add (exact -- no
// running max), then O^T -> O transpose via LDS, coalesced stores.

#define STAGE128(KT2, B) do {                                                 \
    const u16* kt_ = Kh + (size_t)(KT2) * 8192;                               \
    const u16* vt_ = Vh + (size_t)(KT2) * 8192;                               \
    _Pragma("unroll") for (int i_ = 0; i_ < 4; ++i_) {                        \
        int ci_ = i_ * 256 + tid;            /* 0..1023: 128 rows x 8 chks */ \
        gload_lds16(kt_ + (ci_ >> 3) * 64 +                                   \
                    (((ci_ & 7) ^ ((ci_ >> 3) & 7)) * 8),                     \
                    SMEM[B][0] + ci_ * 8);                                    \
        gload_lds16(vt_ + (ci_ >> 3) * 64 +                                   \
                    (((ci_ & 7) ^ ((ci_ >> 3) & 7)) * 8),                     \
                    SMEM[B][1] + ci_ * 8);                                    \
    }                                                                         \
} while (0)

// one PV k-slice SG with preloaded V-frags; BFR = P^T frag (4 u32)
#define PVSTEP(SG, BFR, O0, O1) do {                                          \
    bf8 pf_ = __builtin_bit_cast(bf8, BFR);                                   \
    O0 = mfma32(vfl[SG], pf_, O0);                                            \
    O1 = mfma32(vfh[SG], pf_, O1);                                            \
} while (0)

// pack 32 S^T values -> 8 u32, exchange halves via permlane32_swap (outputs
// are exactly the two B-frag words -- R16/R17-verified mapping), then PV.
#define REPACK_PV(ST, SG0, SG1, O0, O1) do {                                  \
    u32 pk_[8];                                                               \
    _Pragma("unroll") for (int j = 0; j < 8; ++j)                             \
        pk_[j] = pk2(ST[2 * j], ST[2 * j + 1]);                               \
    pl32swap(pk_[0], pk_[2]); pl32swap(pk_[1], pk_[3]);                       \
    pl32swap(pk_[4], pk_[6]); pl32swap(pk_[5], pk_[7]);                       \
    u32x4v f0_ = {pk_[0], pk_[1], pk_[2], pk_[3]};                            \
    u32x4v f1_ = {pk_[4], pk_[5], pk_[6], pk_[7]};                            \
    PVSTEP(SG0, f0_, O0, O1);                                                 \
    PVSTEP(SG1, f1_, O0, O1);                                                 \
} while (0)

// balanced tree sum of 16 floats (no 16-deep serial chain)
#define TREE16(S)                                                             \
    (((((S)[0] + (S)[1]) + ((S)[2] + (S)[3])) +                               \
      (((S)[4] + (S)[5]) + ((S)[6] + (S)[7]))) +                              \
     ((((S)[8] + (S)[9]) + ((S)[10] + (S)[11])) +                             \
      (((S)[12] + (S)[13]) + ((S)[14] + (S)[15]))))

// QK^T + softmax + repack+PV for one q-tile (S^T layout, R16-verified masks)
#define TILE_BODY(QF, QR, DIAG, USEK1, LACC, O0, O1) do {                     \
    f32x16 sT0, sT1;                                                          \
    _Pragma("unroll") for (int r = 0; r < 16; ++r) { sT0[r] = 0.f; sT1[r] = 0.f; } \
    _Pragma("unroll") for (int d = 0; d < 4; ++d)                             \
        sT0 = mfma32(kf0[d], QF[d], sT0);                                     \
    if (USEK1) {                                                              \
        _Pragma("unroll") for (int d = 0; d < 4; ++d)                         \
            sT1 = mfma32(kf1[d], QF[d], sT1);                                 \
    }                                                                         \
    int qg_ = (QR) + l31;                                                     \
    if (DIAG) {                                                               \
        _Pragma("unroll") for (int r = 0; r < 16; ++r) {                      \
            int krow = kb0 + (r & 3) + 8 * (r >> 2) + 4 * h;                  \
            sT0[r] = fexp2(krow <= qg_ ? sT0[r] : -1e30f);                    \
        }                                                                     \
        if (USEK1) {                                                          \
            _Pragma("unroll") for (int r = 0; r < 16; ++r) {                  \
                int krow = kb0 + 32 + (r & 3) + 8 * (r >> 2) + 4 * h;         \
                sT1[r] = fexp2(krow <= qg_ ? sT1[r] : -1e30f);                \
            }                                                                 \
        }                                                                     \
    } else {                                                                  \
        _Pragma("unroll") for (int r = 0; r < 16; ++r) sT0[r] = fexp2(sT0[r]);\
        _Pragma("unroll") for (int r = 0; r < 16; ++r) sT1[r] = fexp2(sT1[r]);\
    }                                                                         \
    LACC += TREE16(sT0);                                                      \
    if (USEK1) LACC += TREE16(sT1);                                           \
    REPACK_PV(sT0, 0, 1, O0, O1);                                             \
    if (USEK1) REPACK_PV(sT1, 2, 3, O0, O1);                                  \
} while (0)

__global__ __launch_bounds__(256, 2) void k_attn(const u16* __restrict__ Qb,
                                                 const u16* __restrict__ Kb,
                                                 const u16* __restrict__ Vtb,
                                                 u16* __restrict__ AO) {
    // 512 blocks; same-head blocks share id%8 (XCD L2 affinity). Longest first.
    int id = blockIdx.x;                     // 0..511
    int bh = (id & 7) * 4 + ((id >> 3) & 3); // head-batch 0..31
    int t  = 15 - (id >> 5);                 // 0..15
    int tid = threadIdx.x;                   // 0..255
    int w = tid >> 6, lane = tid & 63, l31 = lane & 31, h = lane >> 5;
    int a = w & 1, p = w >> 1;               // q-slot, key parity

    const u16* Qh = Qb  + (size_t)bh * 131072;
    const u16* Kh = Kb  + (size_t)bh * 131072;
    const u16* Vh = Vtb + (size_t)bh * 131072;      // V^T tiled: [kt][d][t64]

    __shared__ u16 SMEM[2][2][8192];         // [buf][K|V][image] = 64KB

    int tqA = 4 * t + a, tqB = tqA + 2;      // this slot's two q-tiles
    int qrA = tqA * 32, qrB = tqB * 32;
    int ktA = 2 * t, ktB = 2 * t + 1;        // ktmax per tile (wave-invariant)
    int nk2 = t + 1;                         // block-uniform 128-key stages
    bool odd = (a == 1);                     // tq parity (diag upper-half use)

    // Q^T fragments (B-operand): lane reads its own q-row, 4 d-slices.
    bf8 qfA[4], qfB[4];
#pragma unroll
    for (int s = 0; s < 4; ++s) {
        qfA[s] = *(const bf8*)(Qh + (size_t)(qrA + l31) * 64 + s * 16 + h * 8);
        qfB[s] = *(const bf8*)(Qh + (size_t)(qrB + l31) * 64 + s * 16 + h * 8);
    }

    float lA = 0.f, lB = 0.f;
    f32x16 oA0, oA1, oB0, oB1;
#pragma unroll
    for (int r = 0; r < 16; ++r) {
        oA0[r] = 0.f; oA1[r] = 0.f; oB0[r] = 0.f; oB1[r] = 0.f;
    }

    int swz = l31 & 7;                       // unified read-side XOR selector

    STAGE128(0, 0);
    for (int k2 = 0; k2 < nk2; ++k2) {
        int pb = k2 & 1;
        __syncthreads();                     // drains buf[pb] staging
        if (k2 + 1 < nk2) STAGE128(k2 + 1, pb ^ 1);

        int kt = 2 * k2 + p;                 // this wave's parity sub-tile
        // tile B is active at every stage (kt <= 2t+1 always); tile A until 2t.
        bool aAct  = (kt <= ktA);
        bool diagA = (kt == ktA);            // reachable only for p==0
        bool diagB = (kt == ktB);            // reachable only for p==1
        bool useK1A = aAct && (!diagA || odd);
        bool useK1B = (!diagB || odd);
        const u16* kb_ = SMEM[pb][0] + p * 4096;
        const u16* vb_ = SMEM[pb][1] + p * 4096;
        int kb0 = kt * 64;

        // K-frags once per stage (shared by both tiles)
        bf8 kf0[4], kf1[4];
#pragma unroll
        for (int d = 0; d < 4; ++d)
            kf0[d] = *(const bf8*)(kb_ + l31 * 64 + (((2 * d + h) ^ swz) * 8));
        if (useK1A || useK1B) {
#pragma unroll
            for (int d = 0; d < 4; ++d)
                kf1[d] = *(const bf8*)(kb_ + (32 + l31) * 64 +
                                       (((2 * d + h) ^ swz) * 8));
        }
        // V-frags once per stage (shared by both tiles)
        bf8 vfl[4], vfh[4];
#pragma unroll
        for (int sg = 0; sg < 4; ++sg) {
            vfl[sg] = *(const bf8*)(vb_ + l31 * 64 + (((2 * sg + h) ^ swz) * 8));
            vfh[sg] = *(const bf8*)(vb_ + (32 + l31) * 64 +
                                    (((2 * sg + h) ^ swz) * 8));
        }

        if (aAct) TILE_BODY(qfA, qrA, diagA, useK1A, lA, oA0, oA1);
        TILE_BODY(qfB, qrB, diagB, useK1B, lB, oB0, oB1);
    }

    // ---- split-K combine: parity-1 -> LDS, parity-0 adds (exact) ----
    __syncthreads();                         // all KV reads done
    float* comb = (float*)&SMEM[0][0][0];    // 4*64*36 floats = 36KB
    if (p == 1) {
        float* cwA = comb + ((a * 2 + 0) * 64 + lane) * 36;
        float* cwB = comb + ((a * 2 + 1) * 64 + lane) * 36;
#pragma unroll
        for (int r = 0; r < 16; ++r) {
            cwA[r] = oA0[r]; cwA[16 + r] = oA1[r];
            cwB[r] = oB0[r]; cwB[16 + r] = oB1[r];
        }
        cwA[32] = lA; cwB[32] = lB;
    }
    __syncthreads();
    if (p == 1) return;                      // no barriers below

    const float* crA = comb + ((a * 2 + 0) * 64 + lane) * 36;
    const float* crB = comb + ((a * 2 + 1) * 64 + lane) * 36;
#pragma unroll
    for (int r = 0; r < 16; ++r) {
        oA0[r] += crA[r]; oA1[r] += crA[16 + r];
        oB0[r] += crB[r]; oB1[r] += crB[16 + r];
    }
    lA += crA[32]; lB += crB[32];

    float lsA = lA + __shfl_xor(lA, 32, 64);
    float lsB = lB + __shfl_xor(lB, 32, 64);
    float livA = __builtin_amdgcn_rcpf(lsA);
    float livB = __builtin_amdgcn_rcpf(lsB);

    // ---- epilogue: normalize, transpose O^T -> O via LDS (disjoint region) ----
    u32* OtA = (u32*)&SMEM[0][0][0] + 9216 + (a * 2 + 0) * 1152;  // [32q][36 u32]
    u32* OtB = (u32*)&SMEM[0][0][0] + 9216 + (a * 2 + 1) * 1152;
#pragma unroll
    for (int j = 0; j < 8; ++j) {
        int col = 4 * (j >> 1) + 2 * h + (j & 1);   // d/2 within 32-block
        OtA[l31 * 36 + col]      = pk2(oA0[2 * j] * livA, oA0[2 * j + 1] * livA);
        OtA[l31 * 36 + 16 + col] = pk2(oA1[2 * j] * livA, oA1[2 * j + 1] * livA);
        OtB[l31 * 36 + col]      = pk2(oB0[2 * j] * livB, oB0[2 * j + 1] * livB);
        OtB[l31 * 36 + 16 + col] = pk2(oB1[2 * j] * livB, oB1[2 * j + 1] * livB);
    }
    asm volatile("s_waitcnt lgkmcnt(0)" ::: "memory");
    __builtin_amdgcn_sched_barrier(0);       // rule #18: pin reads after fence

    int q2 = lane >> 1, half = lane & 1;
    int eb = bh >> 4, eh = bh & 15;
    const u32* srcA = OtA + q2 * 36 + half * 16;
    const u32* srcB = OtB + q2 * 36 + half * 16;
    u32* dgA = (u32*)(AO + ((size_t)eb * 2048 + qrA + q2) * 1024 + eh * 64) + half * 16;
    u32* dgB = (u32*)(AO + ((size_t)eb * 2048 + qrB + q2) * 1024 + eh * 64) + half * 16;
#pragma unroll
    for (int c = 0; c < 4; ++c) {
        *(u32x4v*)(dgA + 4 * c) = *(const u32x4v*)(srcA + 4 * c);
        *(u32x4v*)(dgB + 4 * c) = *(const u32x4v*)(srcB + 4 * c);
    }
}

extern "C" void kernel_launch(void* const* d_in, const int* in_sizes, int n_in,
                              void* d_out, int out_size, void* d_ws, size_t ws_size,
                              hipStream_t stream) {
    const float* x  = (const float*)d_in[0];
    const float* Wa = (const float*)d_in[1];
    const float* ba = (const float*)d_in[2];
    const float* Wp = (const float*)d_in[3];
    const float* bp = (const float*)d_in[4];
    float* out = (float*)d_out;

    char* ws = (char*)d_ws;
    const size_t MB = 1024 * 1024;
    u16* Xb  = (u16*)(ws);             // 8 MB  x as bf16   (reused as AO later)
    u16* WtA = (u16*)(ws + 8  * MB);   // 6 MB  W_attn^T bf16
    u16* WtP = (u16*)(ws + 14 * MB);   // 2 MB  W_proj^T bf16
    u16* Qb  = (u16*)(ws + 16 * MB);   // 8 MB  [B*H][T][D], pre-scaled
    u16* Kb  = (u16*)(ws + 24 * MB);   // 8 MB  [B*H][T][D]
    u16* Vtb = (u16*)(ws + 32 * MB);   // 8 MB  [B*H][32][64][64] tiled V^T
    u16* AO  = Xb;                     // alias: Xb dead after k_qkv (stream-ordered)

    k_prep<<<dim3(5120),    dim3(256), 0, stream>>>(x, Wa, Wp, Xb, WtA, WtP);
    k_qkv <<<dim3(32, 24),  dim3(256), 0, stream>>>(Xb, WtA, ba, Qb, Kb, Vtb);
    k_attn<<<dim3(512),     dim3(256), 0, stream>>>(Qb, Kb, Vtb, AO);
    k_proj<<<dim3(32, 8),   dim3(256), 0, stream>>>(AO, WtP, bp, out);
}